// Round 5
// baseline (924.454 us; speedup 1.0000x reference)
//
#include <hip/hip_runtime.h>
#include <hip/hip_bf16.h>

// AdaConv2d: per-sample conv with kernel = base * mask[label[b]] (oc-indep mask).
// B=64, IC=OC=64, H=W=112, 3x3, stride 1, pad 1. ALL float buffers are fp32
// (per harness contract), including d_out.
//
// Round 4 fix: rounds 0-2 wrote bf16 into the fp32 output buffer (harness then
// compared ref[i] vs our out[2i+1] -> absmax sqrt(2)*max|ref| = 8.16, label-
// independent). Round 3's bf16 input reads produced NaN (fp32 mantissa bits as
// bf16) -> proved inputs are fp32. This round: fp32 in, fp32 out.

#define HH 112
#define WW 112
#define IC 64
#define OCN 64
#define FUSE_EPOCH 9
#define TILE 8
#define ICC 8
#define XROW 12   // padded row stride of x tile (10 used)
#define WST 12    // padded per-oc tap stride (9 used)

__global__ __launch_bounds__(256, 2)
void adaconv_kernel(const float* __restrict__ x,
                    const float* __restrict__ kbase,
                    const float* __restrict__ kmask,
                    const int* __restrict__ label,
                    const int* __restrict__ epoch,
                    float* __restrict__ out)
{
    __shared__ float xs[ICC][10][XROW];
    __shared__ float wsm[ICC][OCN][WST];

    const int tid  = threadIdx.x;
    const int tile = blockIdx.x;            // 0..195
    const int b    = blockIdx.y;            // 0..63
    const int ty = tile / 14, tx = tile % 14;
    const int y0 = ty * TILE, x0 = tx * TILE;

    int d = (epoch[0] >= FUSE_EPOCH) ? 0 : label[b];
    d &= 3;  // safety clamp (NDEMOG=4)

    // compute mapping: 16 oc-groups x 16 pixel-groups
    const int ocg  = tid >> 4;              // 0..15 -> oc base ocg*4
    const int pixg = tid & 15;              // 0..15
    const int pgy = pixg >> 2, pgx = pixg & 3;
    const int oy = pgy * 2, ox = pgx * 2;   // pixel base within 8x8 tile

    // weight staging mapping: 64 oc x 4 subsets
    const int woc  = tid & 63;
    const int wsub = tid >> 6;              // ci = wsub, wsub+4

    float acc[4][2][2];
    #pragma unroll
    for (int o = 0; o < 4; ++o)
        #pragma unroll
        for (int r = 0; r < 2; ++r)
            #pragma unroll
            for (int c = 0; c < 2; ++c) acc[o][r][c] = 0.f;

    const float* xb = x + (size_t)b * IC * HH * WW;

    for (int ck = 0; ck < IC / ICC; ++ck) {
        const int icb = ck * ICC;
        __syncthreads();  // WAR guard on LDS reuse

        // ---- stage x chunk: [ICC][10][10] with zero halo ----
        for (int idx = tid; idx < ICC * 100; idx += 256) {
            int ci  = idx / 100;
            int rem = idx - ci * 100;
            int ry  = rem / 10;
            int rx  = rem - ry * 10;
            int gy = y0 - 1 + ry;
            int gx = x0 - 1 + rx;
            float v = 0.f;
            if ((unsigned)gy < HH && (unsigned)gx < WW)
                v = xb[(size_t)(icb + ci) * (HH * WW) + gy * WW + gx];
            xs[ci][ry][rx] = v;
        }

        // ---- stage weights: w = base * mask[d] ----
        #pragma unroll
        for (int s = 0; s < 2; ++s) {
            int ci = wsub + s * 4;
            int ic = icb + ci;
            const float* bp = kbase + ((size_t)woc * IC + ic) * 9;
            const float* mp = kmask + ((size_t)d   * IC + ic) * 9;
            #pragma unroll
            for (int t = 0; t < 9; ++t)
                wsm[ci][woc][t] = bp[t] * mp[t];
        }
        __syncthreads();

        // ---- compute ----
        #pragma unroll
        for (int ci = 0; ci < ICC; ++ci) {
            float xv[4][4];
            #pragma unroll
            for (int r = 0; r < 4; ++r) {
                const float2* p = reinterpret_cast<const float2*>(&xs[ci][oy + r][ox]);
                float2 a = p[0], c2 = p[1];
                xv[r][0] = a.x; xv[r][1] = a.y; xv[r][2] = c2.x; xv[r][3] = c2.y;
            }
            #pragma unroll
            for (int o = 0; o < 4; ++o) {
                const float* wp = &wsm[ci][ocg * 4 + o][0];
                float wv[9];
                #pragma unroll
                for (int t = 0; t < 9; ++t) wv[t] = wp[t];
                #pragma unroll
                for (int r = 0; r < 2; ++r)
                    #pragma unroll
                    for (int c = 0; c < 2; ++c) {
                        float s = acc[o][r][c];
                        #pragma unroll
                        for (int kh = 0; kh < 3; ++kh)
                            #pragma unroll
                            for (int kw = 0; kw < 3; ++kw)
                                s = fmaf(wv[kh * 3 + kw], xv[r + kh][c + kw], s);
                        acc[o][r][c] = s;
                    }
            }
        }
    }

    // ---- write fp32 output ----
    #pragma unroll
    for (int o = 0; o < 4; ++o) {
        int oc = ocg * 4 + o;
        #pragma unroll
        for (int r = 0; r < 2; ++r) {
            int gy = y0 + oy + r;
            size_t base = ((size_t)(b * OCN + oc) * HH + gy) * WW + (x0 + ox);
            float2 v2 = make_float2(acc[o][r][0], acc[o][r][1]);
            *reinterpret_cast<float2*>(&out[base]) = v2;
        }
    }
}

extern "C" void kernel_launch(void* const* d_in, const int* in_sizes, int n_in,
                              void* d_out, int out_size, void* d_ws, size_t ws_size,
                              hipStream_t stream) {
    const float* x  = (const float*)d_in[0];
    const float* kb = (const float*)d_in[1];
    const float* km = (const float*)d_in[2];
    const int*   lb = (const int*)d_in[3];
    const int*   ep = (const int*)d_in[4];
    float* out = (float*)d_out;

    dim3 grid(196, 64);   // 14x14 spatial tiles x 64 samples
    adaconv_kernel<<<grid, 256, 0, stream>>>(x, kb, km, lb, ep, out);
}

// Round 6
// 418.456 us; speedup vs baseline: 2.2092x; 2.2092x over previous
//
#include <hip/hip_runtime.h>
#include <hip/hip_bf16.h>

// AdaConv2d: per-sample conv, kernel = base * mask[label[b]] (oc-indep mask).
// B=64, IC=OC=64, H=W=112, 3x3, pad 1. fp32 in/out (verified round 4).
//
// Round 5: bf16 MFMA implicit GEMM. Per sample: M=64(oc) x K=576(ic*9) x
// N=12544(pixels). Block = sample x (16row x 32col) pixel tile, 4 waves;
// wave = 64oc x 4 rows(32px) = 8x mfma_f32_32x32x16_bf16 acc tiles.
// K-slice per MFMA = (tap, 16 ic): X staged channel-last in LDS so each
// lane's 8 K-contiguous bf16 is one ds_read_b128. Fused bf16 weights
// (base*mask, 4 demog variants) precomputed into d_ws.

#define HH 112
#define WW 112
#define ICn 64
#define OCn 64
#define FUSE_EPOCH 9
#define ICP 24        // padded ic stride in Xs (16 used): conflict-free B-read
#define WSTRIDE 152   // padded W row stride (144 used): conflict-free A-read

typedef __attribute__((ext_vector_type(8))) short short8;
typedef __attribute__((ext_vector_type(8))) unsigned short ushort8;
typedef __attribute__((ext_vector_type(16))) float f32x16;

// ws layout: wf[d][oc][chunk][tap][ic'] bf16, total 4*64*4*9*16 = 147456
__global__ __launch_bounds__(256)
void fuse_w_kernel(const float* __restrict__ kb, const float* __restrict__ km,
                   unsigned short* __restrict__ wf)
{
    int idx = blockIdx.x * 256 + threadIdx.x;
    if (idx >= 4 * 64 * 576) return;
    int ic_ = idx & 15;
    int r = idx >> 4;
    int t = r % 9; r /= 9;
    int ch = r & 3; r >>= 2;
    int oc = r & 63;
    int d = r >> 6;
    int ic = ch * 16 + ic_;
    float v = kb[(oc * ICn + ic) * 9 + t] * km[(d * ICn + ic) * 9 + t];
    __hip_bfloat16 hb = __float2bfloat16(v);
    wf[idx] = *reinterpret_cast<unsigned short*>(&hb);
}

template<bool USE_WS>
__global__ __launch_bounds__(256, 2)
void adaconv_mfma(const float* __restrict__ x,
                  const float* __restrict__ kb,
                  const float* __restrict__ km,
                  const int* __restrict__ label,
                  const int* __restrict__ epoch,
                  const unsigned short* __restrict__ wf,
                  float* __restrict__ out)
{
    __shared__ unsigned short Xs[18][34][ICP];   // 29376 B
    __shared__ unsigned short Ws[64][WSTRIDE];   // 19456 B

    const int tid = threadIdx.x;
    const int b   = blockIdx.y;
    const int bx  = blockIdx.x & 3;     // col tile 0..3 (x0 = 0,32,64,96)
    const int byy = blockIdx.x >> 2;    // row tile 0..6
    const int x0 = bx * 32, y0 = byy * 16;

    int d = (epoch[0] >= FUSE_EPOCH) ? 0 : label[b];
    d &= 3;

    const int w    = tid >> 6;          // wave 0..3 -> rows 4w..4w+3
    const int lane = tid & 63;
    const int ln   = lane & 31;         // M-row (A) / pixel col (B/C)
    const int h    = lane >> 5;         // K-half selector

    f32x16 acc[2][4];
    #pragma unroll
    for (int m = 0; m < 2; ++m)
        #pragma unroll
        for (int j = 0; j < 4; ++j)
            #pragma unroll
            for (int k = 0; k < 16; ++k) acc[m][j][k] = 0.f;

    const float* xb = x + (size_t)b * ICn * HH * WW;

    for (int ck = 0; ck < 4; ++ck) {
        const int icb = ck * 16;
        __syncthreads();   // WAR: previous chunk's reads done

        // ---- stage X chunk: rows y0-1..y0+16, cols x0-1..x0+32, 16 ic ----
        for (int idx = tid; idx < 18 * 34 * 16; idx += 256) {
            int ic  = idx / 612;
            int rem = idx - ic * 612;
            int r   = rem / 34;
            int c   = rem - r * 34;
            int gy = y0 - 1 + r;
            int gx = x0 - 1 + c;
            float v = 0.f;
            if ((unsigned)gy < HH && (unsigned)gx < WW)
                v = xb[(size_t)(icb + ic) * (HH * WW) + gy * WW + gx];
            __hip_bfloat16 hb = __float2bfloat16(v);
            Xs[r][c][ic] = *reinterpret_cast<unsigned short*>(&hb);
        }

        // ---- stage fused weights for this chunk: Ws[oc][t*16+ic'] ----
        if (USE_WS) {
            for (int i = tid; i < 64 * 18; i += 256) {   // 1152 x ushort8
                int oc = i / 18;
                int j8 = (i - oc * 18) * 8;
                ushort8 v = *reinterpret_cast<const ushort8*>(
                    wf + (((size_t)(d * 64 + oc) * 4 + ck) * 144) + j8);
                *reinterpret_cast<ushort8*>(&Ws[oc][j8]) = v;
            }
        } else {
            for (int i = tid; i < 9216; i += 256) {
                int ic_ = i & 15;
                int tt  = (i >> 4) % 9;
                int oc  = i / 144;
                int ic  = icb + ic_;
                float v = kb[(oc * ICn + ic) * 9 + tt] * km[(d * ICn + ic) * 9 + tt];
                __hip_bfloat16 hb = __float2bfloat16(v);
                Ws[oc][tt * 16 + ic_] = *reinterpret_cast<unsigned short*>(&hb);
            }
        }
        __syncthreads();

        // ---- MFMA: 9 taps x 4 row-tiles x 2 oc-halves ----
        #pragma unroll
        for (int kh = 0; kh < 3; ++kh) {
            #pragma unroll
            for (int kw = 0; kw < 3; ++kw) {
                const int t = kh * 3 + kw;
                short8 a0 = *reinterpret_cast<const short8*>(&Ws[ln][t * 16 + h * 8]);
                short8 a1 = *reinterpret_cast<const short8*>(&Ws[32 + ln][t * 16 + h * 8]);
                #pragma unroll
                for (int rj = 0; rj < 4; ++rj) {
                    short8 bb = *reinterpret_cast<const short8*>(
                        &Xs[4 * w + rj + kh][ln + kw][h * 8]);
                    acc[0][rj] = __builtin_amdgcn_mfma_f32_32x32x16_bf16(a0, bb, acc[0][rj], 0, 0, 0);
                    acc[1][rj] = __builtin_amdgcn_mfma_f32_32x32x16_bf16(a1, bb, acc[1][rj], 0, 0, 0);
                }
            }
        }
    }

    // ---- store: C/D layout col=lane&31, row=(reg&3)+8*(reg>>2)+4*h ----
    const int xg = x0 + ln;
    if (xg < WW) {
        #pragma unroll
        for (int m = 0; m < 2; ++m) {
            #pragma unroll
            for (int rj = 0; rj < 4; ++rj) {
                const int yg = y0 + 4 * w + rj;
                #pragma unroll
                for (int reg = 0; reg < 16; ++reg) {
                    const int row = (reg & 3) + 8 * (reg >> 2) + 4 * h;
                    const int oc  = m * 32 + row;
                    out[(((size_t)b * OCn + oc) * HH + yg) * WW + xg] = acc[m][rj][reg];
                }
            }
        }
    }
}

extern "C" void kernel_launch(void* const* d_in, const int* in_sizes, int n_in,
                              void* d_out, int out_size, void* d_ws, size_t ws_size,
                              hipStream_t stream) {
    const float* x  = (const float*)d_in[0];
    const float* kb = (const float*)d_in[1];
    const float* km = (const float*)d_in[2];
    const int*   lb = (const int*)d_in[3];
    const int*   ep = (const int*)d_in[4];
    float* out = (float*)d_out;

    const size_t wf_bytes = (size_t)4 * 64 * 576 * 2;  // 294912
    dim3 grid(28, 64);   // 7 row-tiles x 4 col-tiles, 64 samples

    if (ws_size >= wf_bytes) {
        unsigned short* wf = (unsigned short*)d_ws;
        fuse_w_kernel<<<(4 * 64 * 576 + 255) / 256, 256, 0, stream>>>(kb, km, wf);
        adaconv_mfma<true><<<grid, 256, 0, stream>>>(x, kb, km, lb, ep, wf, out);
    } else {
        adaconv_mfma<false><<<grid, 256, 0, stream>>>(x, kb, km, lb, ep, nullptr, out);
    }
}